// Round 3
// baseline (218.361 us; speedup 1.0000x reference)
//
#include <hip/hip_runtime.h>
#include <stdint.h>

// ---------------------------------------------------------------------------
// SNN: x[512,784] -> FC(784->1024)+LIF -> FC(1024->1024)+LIF -> FC(1024->10)+LIF
// T=32, tau=2 (charge v=(v+cur)/2), vth=1, hard reset to 0. Out = counts [512,10].
//
// Layer-0 input current is CONSTANT over time -> only ~3% of neurons ever
// spike; downstream layers are exact sparse sums over active sets (skipping
// exact-0.0 terms is bit-identical to the dense ascending-k fp32 sum).
//
// R2 lesson: float cur[32] per thread spilled to scratch (VGPR_Count=28),
// ~4 GB scratch traffic -> 77 us. Fix: 4 passes of 8 time-accumulators,
// LIF membrane state carried across passes in a register (exact).
// ---------------------------------------------------------------------------

// ---------------- generic 32x32 tiled transpose: src[R][C] -> dst[C][R] -----
__global__ __launch_bounds__(256) void transpose_k(const float* __restrict__ src,
                                                   float* __restrict__ dst,
                                                   int R, int C) {
  __shared__ float t[32][33];
  int c0 = blockIdx.x * 32, r0 = blockIdx.y * 32;
  int lx = threadIdx.x, ly = threadIdx.y;  // 32 x 8
#pragma unroll
  for (int i = 0; i < 32; i += 8) {
    int r = r0 + ly + i, c = c0 + lx;
    if (r < R && c < C) t[ly + i][lx] = src[(size_t)r * C + c];
  }
  __syncthreads();
#pragma unroll
  for (int i = 0; i < 32; i += 8) {
    int c = c0 + ly + i, r = r0 + lx;
    if (c < C && r < R) dst[(size_t)c * R + r] = t[lx][ly + i];
  }
}

// ---------------- layer-0 currents: cur0[b][o] = x[b,:] . W0T[:,o] ----------
__global__ __launch_bounds__(256) void cur0_k(const float* __restrict__ x,
                                              const float* __restrict__ W0T,
                                              float* __restrict__ cur0) {
  int o = ((blockIdx.x & 3) << 8) + threadIdx.x;  // 0..1023
  int bg = (blockIdx.x >> 2) << 3;                // batch group of 8
  float acc[8] = {};
#pragma unroll 8
  for (int k = 0; k < 784; ++k) {
    float w = W0T[(size_t)k * 1024 + o];
#pragma unroll
    for (int bb = 0; bb < 8; ++bb)
      acc[bb] = fmaf(x[(size_t)(bg + bb) * 784 + k], w, acc[bb]);
  }
#pragma unroll
  for (int bb = 0; bb < 8; ++bb)
    cur0[(size_t)(bg + bb) * 1024 + o] = acc[bb];
}

// ---------------- layer-0 LIF + deterministic compaction --------------------
__global__ __launch_bounds__(1024) void compact0_k(const float* __restrict__ cur0,
                                                   const float* __restrict__ b0,
                                                   unsigned* __restrict__ lidx,
                                                   unsigned* __restrict__ lwrd,
                                                   int* __restrict__ n0) {
  int b = blockIdx.x, o = threadIdx.x;
  float cur = cur0[(size_t)b * 1024 + o] + b0[o];
  float v = 0.f;
  unsigned word = 0u;
#pragma unroll
  for (int t = 0; t < 32; ++t) {
    v = v + (cur - v) * 0.5f;            // exact: /2.0 == *0.5f
    if (v >= 1.0f) { word |= 1u << t; v = 0.f; }
  }
  bool act = (word != 0u);
  unsigned long long m = __ballot(act);
  __shared__ int wtot[16], wbase[16];
  int wave = o >> 6, lane = o & 63;
  if (lane == 0) wtot[wave] = __popcll(m);
  __syncthreads();
  if (o == 0) {
    int s = 0;
#pragma unroll
    for (int i = 0; i < 16; ++i) { wbase[i] = s; s += wtot[i]; }
    n0[b] = s;
  }
  __syncthreads();
  if (act) {
    int pos = wbase[wave] + __popcll(m & ((1ull << lane) - 1ull));
    lidx[(size_t)b * 1024 + pos] = (unsigned)o;
    lwrd[(size_t)b * 1024 + pos] = word;
  }
}

// ---------------- layer-1: sparse currents + LIF + compaction ---------------
// One block per batch (1024 threads, thread = output neuron o).
// t is processed in 4 chunks of 8 so the current accumulators fit in VGPRs
// (no scratch spill); membrane state v carries across chunks == exact LIF.
// Ascending-j accumulation == dense ascending-k fp32 sum exactly.
__global__ __launch_bounds__(1024) void layer1_k(const unsigned* __restrict__ lidx,
                                                 const unsigned* __restrict__ lwrd,
                                                 const int* __restrict__ n0,
                                                 const float* __restrict__ W1T,
                                                 const float* __restrict__ b1,
                                                 unsigned* __restrict__ l2idx,
                                                 unsigned* __restrict__ l2wrd,
                                                 int* __restrict__ n2) {
  __shared__ unsigned sidx[1024], swrd[1024];
  int b = blockIdx.x, o = threadIdx.x;
  int nb = n0[b];
  if (o < nb) {
    sidx[o] = lidx[(size_t)b * 1024 + o];
    swrd[o] = lwrd[(size_t)b * 1024 + o];
  }
  __syncthreads();

  float bias = b1[o];
  float v = 0.f;
  unsigned word = 0u;

#pragma unroll 1
  for (int tc = 0; tc < 32; tc += 8) {
    float cur[8] = {};
    // 2-deep weight prefetch (coalesced: thread o reads W1T[k][o])
    float w0 = (nb > 0) ? W1T[(size_t)sidx[0] * 1024 + o] : 0.f;
    float w1 = (nb > 1) ? W1T[(size_t)sidx[1] * 1024 + o] : 0.f;
    for (int j = 0; j < nb; ++j) {
      float wn = (j + 2 < nb) ? W1T[(size_t)sidx[j + 2] * 1024 + o] : 0.f;
      unsigned wd = swrd[j] >> tc;
#pragma unroll
      for (int t = 0; t < 8; ++t)
        cur[t] += ((wd >> t) & 1u) ? w0 : 0.f;
      w0 = w1;
      w1 = wn;
    }
#pragma unroll
    for (int t = 0; t < 8; ++t) {
      float xc = cur[t] + bias;
      v = v + (xc - v) * 0.5f;
      if (v >= 1.0f) { word |= 1u << (tc + t); v = 0.f; }
    }
  }

  bool act = (word != 0u);
  unsigned long long m = __ballot(act);
  __shared__ int wtot[16], wbase[16];
  int wave = o >> 6, lane = o & 63;
  if (lane == 0) wtot[wave] = __popcll(m);
  __syncthreads();
  if (o == 0) {
    int s = 0;
#pragma unroll
    for (int i = 0; i < 16; ++i) { wbase[i] = s; s += wtot[i]; }
    n2[b] = s;
  }
  __syncthreads();
  if (act) {
    int pos = wbase[wave] + __popcll(m & ((1ull << lane) - 1ull));
    l2idx[(size_t)b * 1024 + pos] = (unsigned)o;
    l2wrd[(size_t)b * 1024 + pos] = word;
  }
}

// ---------------- layer-2: sparse FC + LIF + count --------------------------
__global__ __launch_bounds__(320) void layer2_k(const unsigned* __restrict__ l2idx,
                                                const unsigned* __restrict__ l2wrd,
                                                const int* __restrict__ n2,
                                                const float* __restrict__ W2,
                                                const float* __restrict__ b2,
                                                float* __restrict__ out) {
  __shared__ float sW2[10 * 1025];   // +1 pad -> conflict-free
  __shared__ unsigned sidx[1024], swrd[1024];
  __shared__ float scur[320];
  int b = blockIdx.x, tid = threadIdx.x;
  int m = n2[b];
  for (int i = tid; i < 10240; i += 320)
    sW2[(i >> 10) * 1025 + (i & 1023)] = W2[i];
  for (int i = tid; i < m; i += 320) {
    sidx[i] = l2idx[(size_t)b * 1024 + i];
    swrd[i] = l2wrd[(size_t)b * 1024 + i];
  }
  __syncthreads();

  int t = tid / 10, c = tid - t * 10;  // 32 x 10
  float acc = 0.f;
  for (int j = 0; j < m; ++j) {
    unsigned wd = swrd[j];
    float wv = sW2[c * 1025 + sidx[j]];
    acc += ((wd >> t) & 1u) ? wv : 0.f;  // select, no divergence
  }
  scur[t * 10 + c] = acc;
  __syncthreads();

  if (tid < 10) {
    float v = 0.f, cnt = 0.f, bias = b2[tid];
#pragma unroll
    for (int tt = 0; tt < 32; ++tt) {
      float xc = scur[tt * 10 + tid] + bias;
      v = v + (xc - v) * 0.5f;
      if (v >= 1.0f) { cnt += 1.f; v = 0.f; }
    }
    out[(size_t)b * 10 + tid] = cnt;
  }
}

// ---------------------------------------------------------------------------
extern "C" void kernel_launch(void* const* d_in, const int* in_sizes, int n_in,
                              void* d_out, int out_size, void* d_ws, size_t ws_size,
                              hipStream_t stream) {
  const float* x  = (const float*)d_in[0];   // [512,784]
  const float* W0 = (const float*)d_in[1];   // [1024,784]
  const float* b0 = (const float*)d_in[2];   // [1024]
  const float* W1 = (const float*)d_in[3];   // [1024,1024]
  const float* b1 = (const float*)d_in[4];   // [1024]
  const float* W2 = (const float*)d_in[5];   // [10,1024]
  const float* b2 = (const float*)d_in[6];   // [10]
  float* out = (float*)d_out;                // [512,10]

  char* ws = (char*)d_ws;
  size_t off = 0;
  auto alloc = [&](size_t bytes) -> char* {
    char* p = ws + off;
    off += (bytes + 255) & ~(size_t)255;
    return p;
  };
  float*    W0T   = (float*)alloc((size_t)784 * 1024 * 4);    // 3.2 MB
  float*    W1T   = (float*)alloc((size_t)1024 * 1024 * 4);   // 4.2 MB
  float*    cur0  = (float*)alloc((size_t)512 * 1024 * 4);    // 2.1 MB
  unsigned* lidx  = (unsigned*)alloc((size_t)512 * 1024 * 4); // 2.1 MB
  unsigned* lwrd  = (unsigned*)alloc((size_t)512 * 1024 * 4);
  int*      n0    = (int*)alloc((size_t)512 * 4);
  unsigned* l2idx = (unsigned*)alloc((size_t)512 * 1024 * 4);
  unsigned* l2wrd = (unsigned*)alloc((size_t)512 * 1024 * 4);
  int*      n2    = (int*)alloc((size_t)512 * 4);
  (void)ws_size;

  transpose_k<<<dim3(25, 32), dim3(32, 8), 0, stream>>>(W0, W0T, 1024, 784);
  transpose_k<<<dim3(32, 32), dim3(32, 8), 0, stream>>>(W1, W1T, 1024, 1024);
  cur0_k<<<256, 256, 0, stream>>>(x, W0T, cur0);
  compact0_k<<<512, 1024, 0, stream>>>(cur0, b0, lidx, lwrd, n0);
  layer1_k<<<512, 1024, 0, stream>>>(lidx, lwrd, n0, W1T, b1, l2idx, l2wrd, n2);
  layer2_k<<<512, 320, 0, stream>>>(l2idx, l2wrd, n2, W2, b2, out);
}

// Round 4
// 183.337 us; speedup vs baseline: 1.1910x; 1.1910x over previous
//
#include <hip/hip_runtime.h>
#include <stdint.h>

// ---------------------------------------------------------------------------
// SNN: x[512,784] -> FC(784->1024)+LIF -> FC(1024->1024)+LIF -> FC(1024->10)+LIF
// T=32, tau=2 (charge v=(v+cur)/2), vth=1, hard reset to 0. Out = counts [512,10].
//
// Layer-0 current is constant over time -> only ~3% of neurons ever spike;
// downstream layers are exact sparse sums over active sets.
//
// R3 lesson: layer1 was latency-bound, not spill-bound (1024-thr blocks ->
// 2 blocks/CU -> 4 waves/SIMD; VALUBusy 43%). cur0_k ran at 1 wave/SIMD.
// Fix: restructure both for full wave occupancy.
// ---------------------------------------------------------------------------

// ---------------- generic 32x32 tiled transpose: src[R][C] -> dst[C][R] -----
__global__ __launch_bounds__(256) void transpose_k(const float* __restrict__ src,
                                                   float* __restrict__ dst,
                                                   int R, int C) {
  __shared__ float t[32][33];
  int c0 = blockIdx.x * 32, r0 = blockIdx.y * 32;
  int lx = threadIdx.x, ly = threadIdx.y;  // 32 x 8
#pragma unroll
  for (int i = 0; i < 32; i += 8) {
    int r = r0 + ly + i, c = c0 + lx;
    if (r < R && c < C) t[ly + i][lx] = src[(size_t)r * C + c];
  }
  __syncthreads();
#pragma unroll
  for (int i = 0; i < 32; i += 8) {
    int c = c0 + ly + i, r = r0 + lx;
    if (c < C && r < R) dst[(size_t)c * R + r] = t[lx][ly + i];
  }
}

// ---------------- layer-0 currents: cur0[b][o] = x[b,:] . W0T[:,o] ----------
// 1024 blocks x 256 thr (4 blocks/CU, 16 waves/CU). 2 batches per thread.
__global__ __launch_bounds__(256) void cur0_k(const float* __restrict__ x,
                                              const float* __restrict__ W0T,
                                              float* __restrict__ cur0) {
  int o = blockIdx.x * 256 + threadIdx.x;  // gridDim.x = 4
  int bg = blockIdx.y * 2;                 // gridDim.y = 256
  float a0 = 0.f, a1 = 0.f;
  const float* xr0 = x + (size_t)bg * 784;
  const float* xr1 = xr0 + 784;
#pragma unroll 8
  for (int k = 0; k < 784; ++k) {
    float w = W0T[(size_t)k * 1024 + o];
    a0 = fmaf(xr0[k], w, a0);
    a1 = fmaf(xr1[k], w, a1);
  }
  cur0[(size_t)bg * 1024 + o] = a0;
  cur0[(size_t)(bg + 1) * 1024 + o] = a1;
}

// ---------------- layer-0 LIF + deterministic compaction --------------------
__global__ __launch_bounds__(1024) void compact0_k(const float* __restrict__ cur0,
                                                   const float* __restrict__ b0,
                                                   unsigned* __restrict__ lidx,
                                                   unsigned* __restrict__ lwrd,
                                                   int* __restrict__ n0) {
  int b = blockIdx.x, o = threadIdx.x;
  float cur = cur0[(size_t)b * 1024 + o] + b0[o];
  float v = 0.f;
  unsigned word = 0u;
#pragma unroll
  for (int t = 0; t < 32; ++t) {
    v = v + (cur - v) * 0.5f;            // exact: /2.0 == *0.5f
    if (v >= 1.0f) { word |= 1u << t; v = 0.f; }
  }
  bool act = (word != 0u);
  unsigned long long m = __ballot(act);
  __shared__ int wtot[16], wbase[16];
  int wave = o >> 6, lane = o & 63;
  if (lane == 0) wtot[wave] = __popcll(m);
  __syncthreads();
  if (o == 0) {
    int s = 0;
#pragma unroll
    for (int i = 0; i < 16; ++i) { wbase[i] = s; s += wtot[i]; }
    n0[b] = s;
  }
  __syncthreads();
  if (act) {
    int pos = wbase[wave] + __popcll(m & ((1ull << lane) - 1ull));
    lidx[(size_t)b * 1024 + pos] = (unsigned)o;
    lwrd[(size_t)b * 1024 + pos] = word;
  }
}

// ---------------- layer-1: sparse currents + LIF + compaction ---------------
// Grid: (4 o-tiles) x (512 batches), 512 threads = (t-half h) x (256 outputs).
// 4 blocks/CU -> full 32 waves/CU. Weight loaded once per j per half.
// Inner bit-select: sign-mask + AND (+0.0f adds are exact no-ops).
// Compaction per tile into fixed segment [b*1024 + tile*256 ...] -> the
// concatenation of segments is ascending-o, deterministic.
__global__ __launch_bounds__(512) void layer1_k(const unsigned* __restrict__ lidx,
                                                const unsigned* __restrict__ lwrd,
                                                const int* __restrict__ n0,
                                                const float* __restrict__ W1T,
                                                const float* __restrict__ b1,
                                                unsigned* __restrict__ l2idx,
                                                unsigned* __restrict__ l2wrd,
                                                int* __restrict__ n2t) {
  __shared__ unsigned sidx[1024], swrd[1024];
  __shared__ float vmid[256];
  __shared__ unsigned wlo[256];
  __shared__ int wtot[4], wbase[4];
  const int tile = blockIdx.x, b = blockIdx.y;
  const int tid = threadIdx.x;
  const int o256 = tid & 255, h = tid >> 8;
  const int o = tile * 256 + o256;
  const int nb = n0[b];
  for (int i = tid; i < nb; i += 512) {
    sidx[i] = lidx[(size_t)b * 1024 + i];
    swrd[i] = lwrd[(size_t)b * 1024 + i];
  }
  __syncthreads();

  const int toff = h << 4;
  float cur[16] = {};
  float w0 = (nb > 0) ? W1T[(size_t)sidx[0] * 1024 + o] : 0.f;
  float w1 = (nb > 1) ? W1T[(size_t)sidx[1] * 1024 + o] : 0.f;
  for (int j = 0; j < nb; ++j) {
    float wn = (j + 2 < nb) ? W1T[(size_t)sidx[j + 2] * 1024 + o] : 0.f;
    const unsigned wd = swrd[j] >> toff;
    const int wb = __builtin_bit_cast(int, w0);
#pragma unroll
    for (int t = 0; t < 16; ++t) {
      int msk = ((int)(wd << (31 - t))) >> 31;       // -1 if bit t set, else 0
      cur[t] += __builtin_bit_cast(float, wb & msk); // += w or += +0.0f (exact)
    }
    w0 = w1;
    w1 = wn;
  }

  const float bias = b1[o];
  unsigned word = 0u;
  bool act = false;
  unsigned long long m = 0ull;

  if (h == 0) {
    float v = 0.f;
    unsigned wl = 0u;
#pragma unroll
    for (int t = 0; t < 16; ++t) {
      float xc = cur[t] + bias;
      v = v + (xc - v) * 0.5f;
      if (v >= 1.0f) { wl |= 1u << t; v = 0.f; }
    }
    vmid[o256] = v;
    wlo[o256] = wl;
  }
  __syncthreads();
  if (h == 1) {
    float v = vmid[o256];
    word = wlo[o256];
#pragma unroll
    for (int t = 0; t < 16; ++t) {
      float xc = cur[t] + bias;
      v = v + (xc - v) * 0.5f;
      if (v >= 1.0f) { word |= 1u << (16 + t); v = 0.f; }
    }
    act = (word != 0u);
    m = __ballot(act);                 // waves 4..7, wave-uniform branch
    if ((tid & 63) == 0) wtot[o256 >> 6] = __popcll(m);
  }
  __syncthreads();
  if (tid == 0) {
    int s = 0;
#pragma unroll
    for (int i = 0; i < 4; ++i) { wbase[i] = s; s += wtot[i]; }
    n2t[b * 4 + tile] = s;
  }
  __syncthreads();
  if (h == 1 && act) {
    int pos = wbase[o256 >> 6] + __popcll(m & ((1ull << (tid & 63)) - 1ull));
    l2idx[(size_t)b * 1024 + tile * 256 + pos] = (unsigned)o;
    l2wrd[(size_t)b * 1024 + tile * 256 + pos] = word;
  }
}

// ---------------- layer-2: sparse FC + LIF + count --------------------------
// Reads the 4 per-tile segments in order (ascending-o concatenation).
__global__ __launch_bounds__(320) void layer2_k(const unsigned* __restrict__ l2idx,
                                                const unsigned* __restrict__ l2wrd,
                                                const int* __restrict__ n2t,
                                                const float* __restrict__ W2,
                                                const float* __restrict__ b2,
                                                float* __restrict__ out) {
  __shared__ float sW2[10 * 1025];   // +1 pad -> conflict-free
  __shared__ unsigned sidx[1024], swrd[1024];
  __shared__ float scur[320];
  int b = blockIdx.x, tid = threadIdx.x;
  int cnt[4], ofs[4], mtot = 0;
#pragma unroll
  for (int s = 0; s < 4; ++s) {
    cnt[s] = n2t[b * 4 + s];
    ofs[s] = mtot;
    mtot += cnt[s];
  }
  for (int i = tid; i < 10240; i += 320)
    sW2[(i >> 10) * 1025 + (i & 1023)] = W2[i];
#pragma unroll
  for (int s = 0; s < 4; ++s)
    for (int i = tid; i < cnt[s]; i += 320) {
      sidx[ofs[s] + i] = l2idx[(size_t)b * 1024 + s * 256 + i];
      swrd[ofs[s] + i] = l2wrd[(size_t)b * 1024 + s * 256 + i];
    }
  __syncthreads();

  int t = tid / 10, c = tid - t * 10;  // 32 x 10
  float acc = 0.f;
  for (int j = 0; j < mtot; ++j) {
    unsigned wd = swrd[j];
    float wv = sW2[c * 1025 + sidx[j]];
    acc += ((wd >> t) & 1u) ? wv : 0.f;
  }
  scur[t * 10 + c] = acc;
  __syncthreads();

  if (tid < 10) {
    float v = 0.f, cnt2 = 0.f, bias = b2[tid];
#pragma unroll
    for (int tt = 0; tt < 32; ++tt) {
      float xc = scur[tt * 10 + tid] + bias;
      v = v + (xc - v) * 0.5f;
      if (v >= 1.0f) { cnt2 += 1.f; v = 0.f; }
    }
    out[(size_t)b * 10 + tid] = cnt2;
  }
}

// ---------------------------------------------------------------------------
extern "C" void kernel_launch(void* const* d_in, const int* in_sizes, int n_in,
                              void* d_out, int out_size, void* d_ws, size_t ws_size,
                              hipStream_t stream) {
  const float* x  = (const float*)d_in[0];   // [512,784]
  const float* W0 = (const float*)d_in[1];   // [1024,784]
  const float* b0 = (const float*)d_in[2];   // [1024]
  const float* W1 = (const float*)d_in[3];   // [1024,1024]
  const float* b1 = (const float*)d_in[4];   // [1024]
  const float* W2 = (const float*)d_in[5];   // [10,1024]
  const float* b2 = (const float*)d_in[6];   // [10]
  float* out = (float*)d_out;                // [512,10]

  char* ws = (char*)d_ws;
  size_t off = 0;
  auto alloc = [&](size_t bytes) -> char* {
    char* p = ws + off;
    off += (bytes + 255) & ~(size_t)255;
    return p;
  };
  float*    W0T   = (float*)alloc((size_t)784 * 1024 * 4);    // 3.2 MB
  float*    W1T   = (float*)alloc((size_t)1024 * 1024 * 4);   // 4.2 MB
  float*    cur0  = (float*)alloc((size_t)512 * 1024 * 4);    // 2.1 MB
  unsigned* lidx  = (unsigned*)alloc((size_t)512 * 1024 * 4); // 2.1 MB
  unsigned* lwrd  = (unsigned*)alloc((size_t)512 * 1024 * 4);
  int*      n0    = (int*)alloc((size_t)512 * 4);
  unsigned* l2idx = (unsigned*)alloc((size_t)512 * 1024 * 4);
  unsigned* l2wrd = (unsigned*)alloc((size_t)512 * 1024 * 4);
  int*      n2t   = (int*)alloc((size_t)512 * 4 * 4);
  (void)ws_size;

  transpose_k<<<dim3(25, 32), dim3(32, 8), 0, stream>>>(W0, W0T, 1024, 784);
  transpose_k<<<dim3(32, 32), dim3(32, 8), 0, stream>>>(W1, W1T, 1024, 1024);
  cur0_k<<<dim3(4, 256), 256, 0, stream>>>(x, W0T, cur0);
  compact0_k<<<512, 1024, 0, stream>>>(cur0, b0, lidx, lwrd, n0);
  layer1_k<<<dim3(4, 512), 512, 0, stream>>>(lidx, lwrd, n0, W1T, b1, l2idx, l2wrd, n2t);
  layer2_k<<<512, 320, 0, stream>>>(l2idx, l2wrd, n2t, W2, b2, out);
}

// Round 5
// 160.428 us; speedup vs baseline: 1.3611x; 1.1428x over previous
//
#include <hip/hip_runtime.h>
#include <stdint.h>

// ---------------------------------------------------------------------------
// SNN: x[512,784] -> FC(784->1024)+LIF -> FC(1024->1024)+LIF -> FC(1024->10)+LIF
// T=32, tau=2 (charge v=(v+cur)/2), vth=1, hard reset to 0. Out = counts [512,10].
//
// Layer-0 current is constant over time -> spike trains are EXACTLY periodic
// (after each hard reset the fp recurrence restarts from v=0 with the same
// cur): spikes at t = n-1, 2n-1, ... with n = ctz(word)+1 in [1,32]. So
// cur1[t] = sum_n S_n * [(t+1) % n == 0], a divisor sum over <=32 class
// weight-sums S_n. Class-grouped summation reorders fp adds by ~1 ulp; R1's
// MFMA variant (fully scrambled order) passed absmax=0, so this is safe.
// Layer-0's own k-sum stays strictly ascending (period boundaries cluster
// near cur=1; reorder there is NOT safe).
//
// R4 lesson: layer1 was VALU-issue-bound at 84% busy (4 VALU per (j,t-bit));
// the fix is fewer instructions, not more occupancy.
// ---------------------------------------------------------------------------

// ---------------- generic 32x32 tiled transpose: src[R][C] -> dst[C][R] -----
__global__ __launch_bounds__(256) void transpose_k(const float* __restrict__ src,
                                                   float* __restrict__ dst,
                                                   int R, int C) {
  __shared__ float t[32][33];
  int c0 = blockIdx.x * 32, r0 = blockIdx.y * 32;
  int lx = threadIdx.x, ly = threadIdx.y;  // 32 x 8
#pragma unroll
  for (int i = 0; i < 32; i += 8) {
    int r = r0 + ly + i, c = c0 + lx;
    if (r < R && c < C) t[ly + i][lx] = src[(size_t)r * C + c];
  }
  __syncthreads();
#pragma unroll
  for (int i = 0; i < 32; i += 8) {
    int c = c0 + ly + i, r = r0 + lx;
    if (c < C && r < R) dst[(size_t)c * R + r] = t[lx][ly + i];
  }
}

// ---------------- layer-0 currents: cur0[b][o] = x[b,:] . W0T[:,o] ----------
// 512 threads = 256 o x 2 b-quads; 4 batches per thread (ascending-k chain
// per (b,o) preserved exactly). Grid 4 o-tiles x 64 b-groups = 256 blocks;
// W0T L2 traffic 0.8 MB x 256 = 205 MB (~6 us at L2 BW).
__global__ __launch_bounds__(512) void cur0_k(const float* __restrict__ x,
                                              const float* __restrict__ W0T,
                                              float* __restrict__ cur0) {
  int o = blockIdx.x * 256 + (threadIdx.x & 255);
  int b0 = blockIdx.y * 8 + (threadIdx.x >> 8) * 4;   // 4 batches
  const float* xr = x + (size_t)b0 * 784;
  float a0 = 0.f, a1 = 0.f, a2 = 0.f, a3 = 0.f;
#pragma unroll 8
  for (int k = 0; k < 784; ++k) {
    float w = W0T[(size_t)k * 1024 + o];
    a0 = fmaf(xr[k], w, a0);
    a1 = fmaf(xr[784 + k], w, a1);
    a2 = fmaf(xr[1568 + k], w, a2);
    a3 = fmaf(xr[2352 + k], w, a3);
  }
  cur0[(size_t)b0 * 1024 + o] = a0;
  cur0[(size_t)(b0 + 1) * 1024 + o] = a1;
  cur0[(size_t)(b0 + 2) * 1024 + o] = a2;
  cur0[(size_t)(b0 + 3) * 1024 + o] = a3;
}

// ---------------- layer-0 LIF + class-grouped deterministic compaction ------
// One block per batch (1024 threads = 16 waves). Active neuron -> period
// class n = ctz(word)+1. Stable counting sort (class-major, ascending-o
// within class) via per-class wave ballots -> lidx16 + 33 segment offsets.
__global__ __launch_bounds__(1024) void compact0_k(const float* __restrict__ cur0,
                                                   const float* __restrict__ b0,
                                                   unsigned short* __restrict__ lidx16,
                                                   int* __restrict__ segs) {
  __shared__ int whist[16][33];
  __shared__ int clstot[33];
  __shared__ int clsofs[34];
  __shared__ int wofs[16][33];
  int b = blockIdx.x, o = threadIdx.x;
  int wave = o >> 6, lane = o & 63;

  float cur = cur0[(size_t)b * 1024 + o] + b0[o];
  float v = 0.f;
  unsigned word = 0u;
#pragma unroll
  for (int t = 0; t < 32; ++t) {
    v = v + (cur - v) * 0.5f;            // exact: /2.0 == *0.5f
    if (v >= 1.0f) { word |= 1u << t; v = 0.f; }
  }
  int n = word ? (__builtin_ctz(word) + 1) : 0;   // period class, 0 = inactive

  unsigned long long mymask = 0ull;
#pragma unroll 1
  for (int c = 1; c <= 32; ++c) {
    unsigned long long m = __ballot(n == c);
    if (lane == 0) whist[wave][c] = __popcll(m);
    if (n == c) mymask = m;
  }
  __syncthreads();
  if (o < 32) {                       // totals per class
    int c = o + 1, s = 0;
#pragma unroll
    for (int w = 0; w < 16; ++w) s += whist[w][c];
    clstot[c] = s;
  }
  __syncthreads();
  if (o == 0) {                       // exclusive scan over classes
    int run = 0;
#pragma unroll
    for (int c = 1; c <= 32; ++c) { clsofs[c] = run; run += clstot[c]; }
    clsofs[33] = run;                 // total actives
  }
  __syncthreads();
  if (o < 32) {                       // per-wave offsets within class
    int c = o + 1, s = clsofs[c];
#pragma unroll
    for (int w = 0; w < 16; ++w) { wofs[w][c] = s; s += whist[w][c]; }
  }
  __syncthreads();
  if (n) {
    int pos = wofs[wave][n] + __popcll(mymask & ((1ull << lane) - 1ull));
    lidx16[(size_t)b * 1024 + pos] = (unsigned short)o;
  }
  if (o < 33) segs[b * 33 + o] = clsofs[o + 1];   // segs[c-1]=start(c), segs[32]=end
}

// ---------------- layer-1: class-sum + divisor-table LIF + compaction -------
// Grid (4 o-tiles) x (512 batches), 256 threads (thread = output o).
// Phase 1: S_n = sum of W1T column values over class-n segment (ascending-o
// within class). Phase 2: straight-line LIF; cur at step t = sum of S_n over
// n dividing t+1 (compile-time divisor table). Absent classes give exact +0.
__global__ __launch_bounds__(256) void layer1_k(const unsigned short* __restrict__ lidx16,
                                                const int* __restrict__ segs,
                                                const float* __restrict__ W1T,
                                                const float* __restrict__ b1,
                                                unsigned* __restrict__ l2idx,
                                                unsigned* __restrict__ l2wrd,
                                                int* __restrict__ n2t) {
  __shared__ unsigned short sidx[1024];
  __shared__ int sseg[33];
  __shared__ int wtot[4], wbase[4];
  const int tile = blockIdx.x, b = blockIdx.y;
  const int tid = threadIdx.x;
  const int o = tile * 256 + tid;

  if (tid < 33) sseg[tid] = segs[b * 33 + tid];
  __syncthreads();
  const int total = __builtin_amdgcn_readfirstlane(sseg[32]);
  for (int i = tid; i < total; i += 256)
    sidx[i] = lidx16[(size_t)b * 1024 + i];
  __syncthreads();

  float S[32];
#pragma unroll
  for (int c = 0; c < 32; ++c) {
    int j0 = __builtin_amdgcn_readfirstlane((c == 0) ? 0 : sseg[c - 1]);
    int j1 = __builtin_amdgcn_readfirstlane(sseg[c]);
    float s = 0.f;
    for (int j = j0; j < j1; ++j)
      s += W1T[(size_t)sidx[j] * 1024 + o];
    S[c] = s;
  }

  const float bias = b1[o];
  float v = 0.f;
  unsigned word = 0u;
#pragma unroll
  for (int t = 0; t < 32; ++t) {
    float cur = 0.f;
#pragma unroll
    for (int c = 1; c <= 32; ++c)
      if ((t + 1) % c == 0) cur += S[c - 1];   // compile-time divisor table
    float xc = cur + bias;
    v = v + (xc - v) * 0.5f;
    if (v >= 1.0f) { word |= 1u << t; v = 0.f; }
  }

  bool act = (word != 0u);
  unsigned long long m = __ballot(act);
  int wave = tid >> 6, lane = tid & 63;
  if (lane == 0) wtot[wave] = __popcll(m);
  __syncthreads();
  if (tid == 0) {
    int s = 0;
#pragma unroll
    for (int i = 0; i < 4; ++i) { wbase[i] = s; s += wtot[i]; }
    n2t[b * 4 + tile] = s;
  }
  __syncthreads();
  if (act) {
    int pos = wbase[wave] + __popcll(m & ((1ull << lane) - 1ull));
    l2idx[(size_t)b * 1024 + tile * 256 + pos] = (unsigned)o;
    l2wrd[(size_t)b * 1024 + tile * 256 + pos] = word;
  }
}

// ---------------- layer-2: sparse FC + LIF + count --------------------------
__global__ __launch_bounds__(320) void layer2_k(const unsigned* __restrict__ l2idx,
                                                const unsigned* __restrict__ l2wrd,
                                                const int* __restrict__ n2t,
                                                const float* __restrict__ W2,
                                                const float* __restrict__ b2,
                                                float* __restrict__ out) {
  __shared__ float sW2[10 * 1025];   // +1 pad -> conflict-free
  __shared__ unsigned sidx[1024], swrd[1024];
  __shared__ float scur[320];
  int b = blockIdx.x, tid = threadIdx.x;
  int cnt[4], ofs[4], mtot = 0;
#pragma unroll
  for (int s = 0; s < 4; ++s) {
    cnt[s] = n2t[b * 4 + s];
    ofs[s] = mtot;
    mtot += cnt[s];
  }
  for (int i = tid; i < 10240; i += 320)
    sW2[(i >> 10) * 1025 + (i & 1023)] = W2[i];
#pragma unroll
  for (int s = 0; s < 4; ++s)
    for (int i = tid; i < cnt[s]; i += 320) {
      sidx[ofs[s] + i] = l2idx[(size_t)b * 1024 + s * 256 + i];
      swrd[ofs[s] + i] = l2wrd[(size_t)b * 1024 + s * 256 + i];
    }
  __syncthreads();

  int t = tid / 10, c = tid - t * 10;  // 32 x 10
  float acc = 0.f;
  for (int j = 0; j < mtot; ++j) {
    unsigned wd = swrd[j];
    float wv = sW2[c * 1025 + sidx[j]];
    acc += ((wd >> t) & 1u) ? wv : 0.f;
  }
  scur[t * 10 + c] = acc;
  __syncthreads();

  if (tid < 10) {
    float v = 0.f, cnt2 = 0.f, bias = b2[tid];
#pragma unroll
    for (int tt = 0; tt < 32; ++tt) {
      float xc = scur[tt * 10 + tid] + bias;
      v = v + (xc - v) * 0.5f;
      if (v >= 1.0f) { cnt2 += 1.f; v = 0.f; }
    }
    out[(size_t)b * 10 + tid] = cnt2;
  }
}

// ---------------------------------------------------------------------------
extern "C" void kernel_launch(void* const* d_in, const int* in_sizes, int n_in,
                              void* d_out, int out_size, void* d_ws, size_t ws_size,
                              hipStream_t stream) {
  const float* x  = (const float*)d_in[0];   // [512,784]
  const float* W0 = (const float*)d_in[1];   // [1024,784]
  const float* b0 = (const float*)d_in[2];   // [1024]
  const float* W1 = (const float*)d_in[3];   // [1024,1024]
  const float* b1 = (const float*)d_in[4];   // [1024]
  const float* W2 = (const float*)d_in[5];   // [10,1024]
  const float* b2 = (const float*)d_in[6];   // [10]
  float* out = (float*)d_out;                // [512,10]

  char* ws = (char*)d_ws;
  size_t off = 0;
  auto alloc = [&](size_t bytes) -> char* {
    char* p = ws + off;
    off += (bytes + 255) & ~(size_t)255;
    return p;
  };
  float*          W0T    = (float*)alloc((size_t)784 * 1024 * 4);
  float*          W1T    = (float*)alloc((size_t)1024 * 1024 * 4);
  float*          cur0   = (float*)alloc((size_t)512 * 1024 * 4);
  unsigned short* lidx16 = (unsigned short*)alloc((size_t)512 * 1024 * 2);
  int*            segs   = (int*)alloc((size_t)512 * 33 * 4);
  unsigned*       l2idx  = (unsigned*)alloc((size_t)512 * 1024 * 4);
  unsigned*       l2wrd  = (unsigned*)alloc((size_t)512 * 1024 * 4);
  int*            n2t    = (int*)alloc((size_t)512 * 4 * 4);
  (void)ws_size;

  transpose_k<<<dim3(25, 32), dim3(32, 8), 0, stream>>>(W0, W0T, 1024, 784);
  transpose_k<<<dim3(32, 32), dim3(32, 8), 0, stream>>>(W1, W1T, 1024, 1024);
  cur0_k<<<dim3(4, 64), 512, 0, stream>>>(x, W0T, cur0);
  compact0_k<<<512, 1024, 0, stream>>>(cur0, b0, lidx16, segs);
  layer1_k<<<dim3(4, 512), 256, 0, stream>>>(lidx16, segs, W1T, b1, l2idx, l2wrd, n2t);
  layer2_k<<<512, 320, 0, stream>>>(l2idx, l2wrd, n2t, W2, b2, out);
}